// Round 3
// baseline (367.054 us; speedup 1.0000x reference)
//
#include <hip/hip_runtime.h>

// Problem constants
#define B_TOT 65536
#define WS_D   0               // 8 partial D arrays: 8*256 f32 = 8192 B
#define WS_P1W 8192            // permuted bf16 p1W: 48*512*2 = 49152 B
#define WS_EV  (1u << 20)      // per-batch blocks: 512B E + 1024B V = 1536 B * 65536

typedef float f32x4 __attribute__((ext_vector_type(4)));
typedef short s16x8 __attribute__((ext_vector_type(8)));

__device__ __forceinline__ float bf2f(unsigned short h) {
    unsigned u = ((unsigned)h) << 16;
    return __builtin_bit_cast(float, u);
}
// cheap bf16 pair pack: round-half-up (add 0x8000) + v_perm_b32 high-half merge.
__device__ __forceinline__ unsigned pack2(float a, float b) {
    unsigned ua = __builtin_bit_cast(unsigned, a) + 0x8000u;
    unsigned ub = __builtin_bit_cast(unsigned, b) + 0x8000u;
    return __builtin_amdgcn_perm(ub, ua, 0x07060302u);  // lo16=a, hi16=b
}
__device__ __forceinline__ unsigned short f2bf(float f) {
    return (unsigned short)((__builtin_bit_cast(unsigned, f) + 0x8000u) >> 16);
}
__device__ __forceinline__ s16x8 cvt8(float4 a, float4 b) {
    uint4 u;
    u.x = pack2(a.x, a.y); u.y = pack2(a.z, a.w);
    u.z = pack2(b.x, b.y); u.w = pack2(b.z, b.w);
    return __builtin_bit_cast(s16x8, u);
}
#define MFMA(a, b, c) __builtin_amdgcn_mfma_f32_16x16x32_bf16((a), (b), (c), 0, 0, 0)

// ---------------------------------------------------------------------------
// k0: zero the 8 partial softmax-denominator arrays; build bf16 p1W permuted
// into the i' order k2's H uses.  i' = e_lo*32 + q*8 + h*4 + r,
// original index = (q*4+r)*32 + (e_lo + 16*h).
// ---------------------------------------------------------------------------
__global__ __launch_bounds__(256) void k0_prep(const float* __restrict__ p1W,
                                               char* __restrict__ ws) {
    int idx = blockIdx.x * 256 + threadIdx.x;          // 96*256 = 24576 = 48*512
    if (blockIdx.x < 8)
        ((float*)ws)[blockIdx.x * 256 + threadIdx.x] = 0.f;  // D partials
    int jj   = idx & 7;
    int lane = (idx >> 3) & 63;
    int ktnt = idx >> 9;
    int kt = ktnt & 15, nt = ktnt >> 4;
    int n_lo = lane & 15, q8 = lane >> 4;
    int j  = nt * 16 + n_lo;                           // output neuron [0,48)
    int ip = kt * 32 + q8 * 8 + jj;                    // i' in [0,512)
    int e_lo = ip >> 5, qq = (ip >> 3) & 3, hh = (ip >> 2) & 1, r = ip & 3;
    int orig = (qq * 4 + r) * 32 + (e_lo + 16 * hh);
    ((unsigned short*)(ws + WS_P1W))[idx] = f2bf(p1W[j * 512 + orig]);
}

// ---------------------------------------------------------------------------
// k1: 2 batches per wave, fully straight-line & interleaved for ILP.
// Q,K,V linears (bf16 MFMA, bias in accumulator), Q normalized pre-S-MFMA,
// K fed raw (1/||K|| folded into exp argument post-MFMA), E=exp -> ws
// ([d][c] bf16), V -> ws (B-frag blocked bf16), D via 8-way partial atomics.
// 8192 blocks * 4 waves * 2 batches = 65536.
// ---------------------------------------------------------------------------
__global__ __launch_bounds__(256, 3) void k1_stats(
    const float* __restrict__ e1, const float* __restrict__ e2,
    const float* __restrict__ qW, const float* __restrict__ qb,
    const float* __restrict__ kW, const float* __restrict__ kb,
    const float* __restrict__ vW, const float* __restrict__ vb,
    char* __restrict__ ws) {

    const int tid = threadIdx.x;
    const int lane = tid & 63;
    const int widx = tid >> 6;
    const int col = lane & 15;      // n-index (e_lo / d) in MFMA layouts
    const int quad = lane >> 4;

    __shared__ __align__(16) unsigned short qk_lds[4][4][640]; // 20480 B
    __shared__ float Dblk[256];
    Dblk[tid] = 0.f;
    __syncthreads();

    // Weight B-fragments: B_h[k=l][n=e_lo] = W[e_lo+16h][l]
    s16x8 wq[2], wk[2], wv[2];
    f32x4 cbq[2], cbk[2], cbv[2];   // bias pre-loaded into MFMA accumulators
    for (int h = 0; h < 2; ++h) {
        int row = col + 16 * h;
        const float4* pq = (const float4*)(qW + row * 32 + quad * 8);
        const float4* pk = (const float4*)(kW + row * 32 + quad * 8);
        const float4* pv = (const float4*)(vW + row * 32 + quad * 8);
        wq[h] = cvt8(pq[0], pq[1]);
        wk[h] = cvt8(pk[0], pk[1]);
        wv[h] = cvt8(pv[0], pv[1]);
        float qv = qb[row], kv = kb[row], vv = vb[row];
        cbq[h] = (f32x4){qv, qv, qv, qv};
        cbk[h] = (f32x4){kv, kv, kv, kv};
        cbv[h] = (f32x4){vv, vv, vv, vv};
    }

    unsigned short* qb0 = qk_lds[widx][0];
    unsigned short* kb0 = qk_lds[widx][1];
    unsigned short* qb1 = qk_lds[widx][2];
    unsigned short* kb1 = qk_lds[widx][3];
    char* evbase = ws + WS_EV;
    const f32x4 z = {0.f, 0.f, 0.f, 0.f};

    const int gw = blockIdx.x * 4 + widx;
    const int bA = gw * 2, bB = bA + 1;

    // ---- issue ALL global loads up front (8 dwordx4 in flight) ----
    const float4* x1A = (const float4*)(e1 + (size_t)bA * 512 + col * 32 + quad * 8);
    const float4* x2A = (const float4*)(e2 + (size_t)bA * 512 + col * 32 + quad * 8);
    const float4* x1B = (const float4*)(e1 + (size_t)bB * 512 + col * 32 + quad * 8);
    const float4* x2B = (const float4*)(e2 + (size_t)bB * 512 + col * 32 + quad * 8);
    float4 a0A = x1A[0], a1A = x1A[1], b0A = x2A[0], b1A = x2A[1];
    float4 a0B = x1B[0], a1B = x1B[1], b0B = x2B[0], b1B = x2B[1];
    s16x8 fx1A = cvt8(a0A, a1A), fx2A = cvt8(b0A, b1A);
    s16x8 fx1B = cvt8(a0B, a1B), fx2B = cvt8(b0B, b1B);

    // ---- MFMAs + products + LDS writes, batch A then B (indep chains) ----
    float VvA[2][4], VvB[2][4];
    for (int h = 0; h < 2; ++h) {
        f32x4 q1 = MFMA(fx1A, wq[h], cbq[h]), q2 = MFMA(fx2A, wq[h], cbq[h]);
        f32x4 k1 = MFMA(fx1A, wk[h], cbk[h]), k2 = MFMA(fx2A, wk[h], cbk[h]);
        f32x4 v1 = MFMA(fx1A, wv[h], cbv[h]), v2 = MFMA(fx2A, wv[h], cbv[h]);
        f32x4 Qt = q1 * q2, Kt = k1 * k2;
        for (int r = 0; r < 4; ++r) VvA[h][r] = v1[r] * v2[r];
        if (h == 0) {
            for (int r = 0; r < 4; ++r) {
                // stash h=0 halves temporarily in registers via LDS-deferred
                // scheme: store packed later; keep in VGPR arrays
            }
        }
        // store packed pairs needs both h values; buffer h=0 in VGPRs:
        static_assert(true, "");
        if (h == 0) {
            // save for pairing
            for (int r = 0; r < 4; ++r) { VvA[0][r] = VvA[0][r]; }
        }
        (void)Qt; (void)Kt;
    }
    // The loop above can't pair h=0/h=1 for packing; redo explicitly:
    {
        f32x4 q1_0 = MFMA(fx1A, wq[0], cbq[0]), q2_0 = MFMA(fx2A, wq[0], cbq[0]);
        f32x4 q1_1 = MFMA(fx1A, wq[1], cbq[1]), q2_1 = MFMA(fx2A, wq[1], cbq[1]);
        f32x4 k1_0 = MFMA(fx1A, wk[0], cbk[0]), k2_0 = MFMA(fx2A, wk[0], cbk[0]);
        f32x4 k1_1 = MFMA(fx1A, wk[1], cbk[1]), k2_1 = MFMA(fx2A, wk[1], cbk[1]);
        f32x4 v1_0 = MFMA(fx1A, wv[0], cbv[0]), v2_0 = MFMA(fx2A, wv[0], cbv[0]);
        f32x4 v1_1 = MFMA(fx1A, wv[1], cbv[1]), v2_1 = MFMA(fx2A, wv[1], cbv[1]);
        for (int r = 0; r < 4; ++r) {
            VvA[0][r] = v1_0[r] * v2_0[r];
            VvA[1][r] = v1_1[r] * v2_1[r];
            int w = (quad * 4 + r) * 20 + col;
            ((unsigned*)qb0)[w] = pack2(q1_0[r] * q2_0[r], q1_1[r] * q2_1[r]);
            ((unsigned*)kb0)[w] = pack2(k1_0[r] * k2_0[r], k1_1[r] * k2_1[r]);
        }
    }
    {
        f32x4 q1_0 = MFMA(fx1B, wq[0], cbq[0]), q2_0 = MFMA(fx2B, wq[0], cbq[0]);
        f32x4 q1_1 = MFMA(fx1B, wq[1], cbq[1]), q2_1 = MFMA(fx2B, wq[1], cbq[1]);
        f32x4 k1_0 = MFMA(fx1B, wk[0], cbk[0]), k2_0 = MFMA(fx2B, wk[0], cbk[0]);
        f32x4 k1_1 = MFMA(fx1B, wk[1], cbk[1]), k2_1 = MFMA(fx2B, wk[1], cbk[1]);
        f32x4 v1_0 = MFMA(fx1B, wv[0], cbv[0]), v2_0 = MFMA(fx2B, wv[0], cbv[0]);
        f32x4 v1_1 = MFMA(fx1B, wv[1], cbv[1]), v2_1 = MFMA(fx2B, wv[1], cbv[1]);
        for (int r = 0; r < 4; ++r) {
            VvB[0][r] = v1_0[r] * v2_0[r];
            VvB[1][r] = v1_1[r] * v2_1[r];
            int w = (quad * 4 + r) * 20 + col;
            ((unsigned*)qb1)[w] = pack2(q1_0[r] * q2_0[r], q1_1[r] * q2_1[r]);
            ((unsigned*)kb1)[w] = pack2(k1_0[r] * k2_0[r], k1_1[r] * k2_1[r]);
        }
    }

    // ---- LDS readback: A-frag (Q) / B-frag (K) for both batches ----
    s16x8 aqA = *(const s16x8*)(qb0 + col * 40 + quad * 8);
    s16x8 bkA = *(const s16x8*)(kb0 + col * 40 + quad * 8);
    s16x8 aqB = *(const s16x8*)(qb1 + col * 40 + quad * 8);
    s16x8 bkB = *(const s16x8*)(kb1 + col * 40 + quad * 8);

    // ---- norms: Q needs values kept for scaling, K only needs sum-sq ----
    float qvA[8], qvB[8];
    float ssqA = 0.f, ssqB = 0.f, sskA = 0.f, sskB = 0.f;
    for (int j = 0; j < 8; ++j) {
        qvA[j] = bf2f((unsigned short)aqA[j]); ssqA += qvA[j] * qvA[j];
        qvB[j] = bf2f((unsigned short)aqB[j]); ssqB += qvB[j] * qvB[j];
        float ka = bf2f((unsigned short)bkA[j]); sskA += ka * ka;
        float kb_ = bf2f((unsigned short)bkB[j]); sskB += kb_ * kb_;
    }
    ssqA += __shfl_xor(ssqA, 16); sskA += __shfl_xor(sskA, 16);
    ssqB += __shfl_xor(ssqB, 16); sskB += __shfl_xor(sskB, 16);
    ssqA += __shfl_xor(ssqA, 32); sskA += __shfl_xor(sskA, 32);
    ssqB += __shfl_xor(ssqB, 32); sskB += __shfl_xor(sskB, 32);
    float sqA = 1.f / fmaxf(sqrtf(ssqA), 1e-12f);
    float sqB = 1.f / fmaxf(sqrtf(ssqB), 1e-12f);
    float ikA = 1.f / fmaxf(sqrtf(sskA), 1e-12f);
    float ikB = 1.f / fmaxf(sqrtf(sskB), 1e-12f);

    uint4 uq;
    uq.x = pack2(qvA[0] * sqA, qvA[1] * sqA); uq.y = pack2(qvA[2] * sqA, qvA[3] * sqA);
    uq.z = pack2(qvA[4] * sqA, qvA[5] * sqA); uq.w = pack2(qvA[6] * sqA, qvA[7] * sqA);
    s16x8 aqAs = __builtin_bit_cast(s16x8, uq);
    uq.x = pack2(qvB[0] * sqB, qvB[1] * sqB); uq.y = pack2(qvB[2] * sqB, qvB[3] * sqB);
    uq.z = pack2(qvB[4] * sqB, qvB[5] * sqB); uq.w = pack2(qvB[6] * sqB, qvB[7] * sqB);
    s16x8 aqBs = __builtin_bit_cast(s16x8, uq);

    // ---- S MFMAs (K raw; 1/||K_d|| applied post-MFMA, d = col) ----
    f32x4 SA = MFMA(aqAs, bkA, z);   // S[c=quad*4+r][d=col] * ||K_d||
    f32x4 SB = MFMA(aqBs, bkB, z);

    float exA[4], exB[4], dacc[4];
    for (int r = 0; r < 4; ++r) {
        exA[r] = __expf(SA[r] * ikA);
        exB[r] = __expf(SB[r] * ikB);
        dacc[r] = exA[r] + exB[r];
    }

    // ---- stores: E ([d][c] bf16) and V (B-frag blocked) for both ----
    char* baseA = evbase + (size_t)bA * 1536;
    char* baseB = evbase + (size_t)bB * 1536;
    uint2 st;
    st.x = pack2(exA[0], exA[1]); st.y = pack2(exA[2], exA[3]);
    *(uint2*)(baseA + col * 32 + quad * 8) = st;
    st.x = pack2(exB[0], exB[1]); st.y = pack2(exB[2], exB[3]);
    *(uint2*)(baseB + col * 32 + quad * 8) = st;
    for (int h = 0; h < 2; ++h) {
        int voff = 512 + ((h * 16 + col) * 2 + (quad >> 1)) * 16 + (quad & 1) * 8;
        st.x = pack2(VvA[h][0], VvA[h][1]); st.y = pack2(VvA[h][2], VvA[h][3]);
        *(uint2*)(baseA + voff) = st;
        st.x = pack2(VvB[h][0], VvB[h][1]); st.y = pack2(VvB[h][2], VvB[h][3]);
        *(uint2*)(baseB + voff) = st;
    }

    // ---- hierarchical denominator reduce: regs -> block LDS -> 8 partials ----
    for (int r = 0; r < 4; ++r)
        atomicAdd(&Dblk[col * 16 + quad * 4 + r], dacc[r]);
    __syncthreads();
    atomicAdd(((float*)ws) + ((blockIdx.x & 7) << 8) + tid, Dblk[tid]);
}

// ---------------------------------------------------------------------------
// k2: cooperative 4-wave block over ONE 16-batch group.  Phase1: each wave
// computes 4 of the 16 per-batch out[d][e] rows into shared 16KB H (bf16,
// XOR-swizzled).  Phase2: each wave takes 4 of 16 k-tiles of MLP1 (MFMA),
// partials reduced through LDS (aliased over H).  Phase3: wave 0 does
// bias+relu, MLP2, normalize, store.  Grid 4096 blocks.
// ---------------------------------------------------------------------------
__global__ __launch_bounds__(256, 4) void k2_apply(
    const char* __restrict__ ws, const float* __restrict__ p1b,
    const float* __restrict__ p2W, const float* __restrict__ p2b,
    float* __restrict__ out) {

    const int tid = threadIdx.x;
    const int lane = tid & 63;
    const int widx = tid >> 6;
    const int col = lane & 15;
    const int quad = lane >> 4;
    const int qm = quad & 1;        // mirrored address for upper quads

    __shared__ __align__(16) unsigned short Hs[16 * 512];   // 16 KiB
    float* P = (float*)Hs;          // aliased partial-sum buffer (12 KiB)

    // 1/denominator from 8 partial arrays (L2-hot 8KB); c = qm*8+j at row col
    const float* Dws = (const float*)ws;
    float dsum[8] = {0.f, 0.f, 0.f, 0.f, 0.f, 0.f, 0.f, 0.f};
    for (int p = 0; p < 8; ++p) {
        const float4* dp = (const float4*)(Dws + p * 256 + col * 16 + qm * 8);
        float4 a = dp[0], b = dp[1];
        dsum[0] += a.x; dsum[1] += a.y; dsum[2] += a.z; dsum[3] += a.w;
        dsum[4] += b.x; dsum[5] += b.y; dsum[6] += b.z; dsum[7] += b.w;
    }
    float dinv[8];
    for (int j = 0; j < 8; ++j) dinv[j] = 1.f / dsum[j];

    const char* evbase = ws + WS_EV;
    const unsigned short* p1wp = (const unsigned short*)(ws + WS_P1W);
    const int g = blockIdx.x;
    const f32x4 z = {0.f, 0.f, 0.f, 0.f};
    const s16x8 zz = {0, 0, 0, 0, 0, 0, 0, 0};

    // Phase 1: out[d][e] for batches i = widx*4 .. +3 -> H rows (bf16, swizzled)
    for (int ii = 0; ii < 4; ++ii) {
        const int i = widx * 4 + ii;
        const int b = g * 16 + i;
        const char* bbase = evbase + (size_t)b * 1536;
        s16x8 eraw = *(const s16x8*)(bbase + col * 32 + qm * 16);
        s16x8 bf0 = *(const s16x8*)(bbase + 512 + (col * 2 + qm) * 16);
        s16x8 bf1 = *(const s16x8*)(bbase + 512 + ((16 + col) * 2 + qm) * 16);
        float ef[8];
        for (int j = 0; j < 8; ++j)
            ef[j] = bf2f((unsigned short)eraw[j]) * dinv[j];
        uint4 ua;
        ua.x = pack2(ef[0], ef[1]); ua.y = pack2(ef[2], ef[3]);
        ua.z = pack2(ef[4], ef[5]); ua.w = pack2(ef[6], ef[7]);
        s16x8 afrag = __builtin_bit_cast(s16x8, ua);
        if (quad >= 2) { afrag = zz; bf0 = zz; bf1 = zz; }  // K-padding (c>=16 -> 0)
        f32x4 o0 = MFMA(afrag, bf0, z);   // out[d=quad*4+r][e=col]
        f32x4 o1 = MFMA(afrag, bf1, z);   // out[d=quad*4+r][e=col+16]
        uint4 uh;
        uh.x = pack2(o0[0], o0[1]); uh.y = pack2(o0[2], o0[3]);
        uh.z = pack2(o1[0], o1[1]); uh.w = pack2(o1[2], o1[3]);
        int chunk = (col * 4 + quad) ^ (i & 7);   // 16B-chunk XOR swizzle
        *(uint4*)(Hs + i * 512 + chunk * 8) = uh;
    }
    __syncthreads();

    // Phase 2: MLP1 — H[16 x 512] @ p1Wp^T, wave widx handles kt = widx*4..+3
    f32x4 acc[3] = {z, z, z};
    for (int t = 0; t < 4; ++t) {
        int kt = widx * 4 + t;
        int chunk = (kt * 4 + quad) ^ (col & 7);
        s16x8 a = *(const s16x8*)(Hs + col * 512 + chunk * 8);
        for (int nt = 0; nt < 3; ++nt) {
            s16x8 bw = *(const s16x8*)(p1wp + ((nt * 16 + kt) * 64 + lane) * 8);
            acc[nt] = MFMA(a, bw, acc[nt]);
        }
    }
    __syncthreads();   // H reads done before P overwrites it

    // partials -> LDS: P[widx][lane][nt*4+r], lane stride 12 floats (48B)
    for (int nt = 0; nt < 3; ++nt)
        *(f32x4*)(P + (widx * 64 + lane) * 12 + nt * 4) = acc[nt];
    __syncthreads();

    if (widx == 0) {
        // Phase 3: sum partials, bias+relu, MLP2, 16-lane butterfly, normalize
        f32x4 s[3] = {z, z, z};
        for (int w = 0; w < 4; ++w)
            for (int nt = 0; nt < 3; ++nt) {
                f32x4 pv = *(const f32x4*)(P + (w * 64 + lane) * 12 + nt * 4);
                s[nt] += pv;
            }
        float p2w[3][3], p1bias[3];
        for (int nt = 0; nt < 3; ++nt) {
            p1bias[nt] = p1b[col + 16 * nt];
            for (int t = 0; t < 3; ++t) p2w[nt][t] = p2W[t * 48 + col + 16 * nt];
        }
        const float pb0 = p2b[0], pb1 = p2b[1], pb2 = p2b[2];
        float pp[4][3] = {};
        for (int nt = 0; nt < 3; ++nt)
            for (int r = 0; r < 4; ++r) {
                float hv = fmaxf(s[nt][r] + p1bias[nt], 0.f);
                pp[r][0] += hv * p2w[nt][0];
                pp[r][1] += hv * p2w[nt][1];
                pp[r][2] += hv * p2w[nt][2];
            }
        for (int m = 1; m <= 8; m <<= 1)
            for (int r = 0; r < 4; ++r)
                for (int t = 0; t < 3; ++t)
                    pp[r][t] += __shfl_xor(pp[r][t], m);
        for (int r = 0; r < 4; ++r) {
            float h0 = pp[r][0] + pb0, h1 = pp[r][1] + pb1, h2 = pp[r][2] + pb2;
            float inv = 1.f / fmaxf(sqrtf(h0 * h0 + h1 * h1 + h2 * h2), 1e-12f);
            if (col < 3) {
                float v = (col == 0) ? h0 : ((col == 1) ? h1 : h2);
                out[(size_t)(g * 16 + quad * 4 + r) * 3 + col] = v * inv;
            }
        }
    }
}

// ---------------------------------------------------------------------------
extern "C" void kernel_launch(void* const* d_in, const int* in_sizes, int n_in,
                              void* d_out, int out_size, void* d_ws, size_t ws_size,
                              hipStream_t stream) {
    const float* e1  = (const float*)d_in[0];
    const float* e2  = (const float*)d_in[1];
    const float* qW  = (const float*)d_in[2];
    const float* qb  = (const float*)d_in[3];
    const float* kW  = (const float*)d_in[4];
    const float* kb  = (const float*)d_in[5];
    const float* vW  = (const float*)d_in[6];
    const float* vb  = (const float*)d_in[7];
    const float* p1W = (const float*)d_in[8];
    const float* p1b = (const float*)d_in[9];
    const float* p2W = (const float*)d_in[10];
    const float* p2b = (const float*)d_in[11];
    float* out = (float*)d_out;
    char* ws = (char*)d_ws;

    k0_prep<<<96, 256, 0, stream>>>(p1W, ws);
    k1_stats<<<8192, 256, 0, stream>>>(e1, e2, qW, qb, kW, kb, vW, vb, ws);
    k2_apply<<<4096, 256, 0, stream>>>(ws, p1b, p2W, p2b, out);
}

// Round 4
// 346.545 us; speedup vs baseline: 1.0592x; 1.0592x over previous
//
#include <hip/hip_runtime.h>

// Problem constants
#define B_TOT 65536
#define WS_D   0               // 8 partial D arrays: 8*256 f32 = 8192 B
#define WS_P1W 8192            // permuted bf16 p1W: 48*512*2 = 49152 B
#define WS_EV  (1u << 20)      // per-batch blocks: 512B E + 1024B V = 1536 B * 65536

typedef float f32x4 __attribute__((ext_vector_type(4)));
typedef short s16x8 __attribute__((ext_vector_type(8)));

__device__ __forceinline__ float bf2f(unsigned short h) {
    unsigned u = ((unsigned)h) << 16;
    return __builtin_bit_cast(float, u);
}
// cheap bf16 pair pack: round-half-up (add 0x8000) + v_perm_b32 high-half merge.
__device__ __forceinline__ unsigned pack2(float a, float b) {
    unsigned ua = __builtin_bit_cast(unsigned, a) + 0x8000u;
    unsigned ub = __builtin_bit_cast(unsigned, b) + 0x8000u;
    return __builtin_amdgcn_perm(ub, ua, 0x07060302u);  // lo16=a, hi16=b
}
__device__ __forceinline__ unsigned short f2bf(float f) {
    return (unsigned short)((__builtin_bit_cast(unsigned, f) + 0x8000u) >> 16);
}
__device__ __forceinline__ s16x8 cvt8(float4 a, float4 b) {
    uint4 u;
    u.x = pack2(a.x, a.y); u.y = pack2(a.z, a.w);
    u.z = pack2(b.x, b.y); u.w = pack2(b.z, b.w);
    return __builtin_bit_cast(s16x8, u);
}
#define MFMA(a, b, c) __builtin_amdgcn_mfma_f32_16x16x32_bf16((a), (b), (c), 0, 0, 0)

// ---------------------------------------------------------------------------
// k0: zero the 8 partial softmax-denominator arrays; build bf16 p1W permuted
// into the i' order k2's H uses.  i' = e_lo*32 + q*8 + h*4 + r,
// original index = (q*4+r)*32 + (e_lo + 16*h).
// ---------------------------------------------------------------------------
__global__ __launch_bounds__(256) void k0_prep(const float* __restrict__ p1W,
                                               char* __restrict__ ws) {
    int idx = blockIdx.x * 256 + threadIdx.x;          // 96*256 = 24576 = 48*512
    if (blockIdx.x < 8)
        ((float*)ws)[blockIdx.x * 256 + threadIdx.x] = 0.f;  // D partials
    int jj   = idx & 7;
    int lane = (idx >> 3) & 63;
    int ktnt = idx >> 9;
    int kt = ktnt & 15, nt = ktnt >> 4;
    int n_lo = lane & 15, q8 = lane >> 4;
    int j  = nt * 16 + n_lo;                           // output neuron [0,48)
    int ip = kt * 32 + q8 * 8 + jj;                    // i' in [0,512)
    int e_lo = ip >> 5, qq = (ip >> 3) & 3, hh = (ip >> 2) & 1, r = ip & 3;
    int orig = (qq * 4 + r) * 32 + (e_lo + 16 * hh);
    ((unsigned short*)(ws + WS_P1W))[idx] = f2bf(p1W[j * 512 + orig]);
}

// ---------------------------------------------------------------------------
// k1: 8 batches/wave, 3-deep software pipeline:
//   iter i:  [ds_reads for stage2(i-1)] -> stage1(i) -> [global loads i+2]
//            -> stage2(i-1)
// stage1 = QKV MFMAs + pack Q,K to LDS (ping-pong set i&1) + V global store.
// stage2 = Q/K frag read, norms, S MFMA, exp, E store, dacc.
// 2048 blocks * 4 waves * 8 batches = 65536.
// ---------------------------------------------------------------------------
__global__ __launch_bounds__(256, 3) void k1_stats(
    const float* __restrict__ e1, const float* __restrict__ e2,
    const float* __restrict__ qW, const float* __restrict__ qb,
    const float* __restrict__ kW, const float* __restrict__ kb,
    const float* __restrict__ vW, const float* __restrict__ vb,
    char* __restrict__ ws) {

    const int tid = threadIdx.x;
    const int lane = tid & 63;
    const int widx = tid >> 6;
    const int col = lane & 15;      // n-index (e_lo / d) in MFMA layouts
    const int quad = lane >> 4;

    __shared__ __align__(16) unsigned short qk[4][2][2][640]; // [wave][set][q/k][16*40]
    __shared__ float Dblk[256];
    Dblk[tid] = 0.f;
    __syncthreads();

    // Weight B-fragments: B_h[k=l][n=e_lo] = W[e_lo+16h][l]; biases as scalars.
    s16x8 wq[2], wk[2], wv[2];
    float qbs[2], kbs[2], vbs[2];
    for (int h = 0; h < 2; ++h) {
        int row = col + 16 * h;
        const float4* pq = (const float4*)(qW + row * 32 + quad * 8);
        const float4* pk = (const float4*)(kW + row * 32 + quad * 8);
        const float4* pv = (const float4*)(vW + row * 32 + quad * 8);
        wq[h] = cvt8(pq[0], pq[1]);
        wk[h] = cvt8(pk[0], pk[1]);
        wv[h] = cvt8(pv[0], pv[1]);
        qbs[h] = qb[row]; kbs[h] = kb[row]; vbs[h] = vb[row];
    }

    char* evbase = ws + WS_EV;
    const f32x4 z = {0.f, 0.f, 0.f, 0.f};
    float dacc[4] = {0.f, 0.f, 0.f, 0.f};

    const int gw = blockIdx.x * 4 + widx;
    const int base = gw * 8;
    const int xoff = col * 32 + quad * 8;

    float4 L[2][4];
    auto issueL = [&](int slot, int i) {
        const float4* x1 = (const float4*)(e1 + (size_t)(base + i) * 512 + xoff);
        const float4* x2 = (const float4*)(e2 + (size_t)(base + i) * 512 + xoff);
        L[slot][0] = x1[0]; L[slot][1] = x1[1];
        L[slot][2] = x2[0]; L[slot][3] = x2[1];
    };
    auto stage1 = [&](int i) {
        const int s = i & 1;
        s16x8 fx1 = cvt8(L[s][0], L[s][1]);
        s16x8 fx2 = cvt8(L[s][2], L[s][3]);
        f32x4 q10 = MFMA(fx1, wq[0], z), q20 = MFMA(fx2, wq[0], z);
        f32x4 q11 = MFMA(fx1, wq[1], z), q21 = MFMA(fx2, wq[1], z);
        f32x4 k10 = MFMA(fx1, wk[0], z), k20 = MFMA(fx2, wk[0], z);
        f32x4 k11 = MFMA(fx1, wk[1], z), k21 = MFMA(fx2, wk[1], z);
        f32x4 v10 = MFMA(fx1, wv[0], z), v20 = MFMA(fx2, wv[0], z);
        f32x4 v11 = MFMA(fx1, wv[1], z), v21 = MFMA(fx2, wv[1], z);
        unsigned* qlds = (unsigned*)qk[widx][s][0];
        unsigned* klds = (unsigned*)qk[widx][s][1];
        for (int r = 0; r < 4; ++r) {
            int w = (quad * 4 + r) * 20 + col;
            qlds[w] = pack2((q10[r] + qbs[0]) * (q20[r] + qbs[0]),
                            (q11[r] + qbs[1]) * (q21[r] + qbs[1]));
            klds[w] = pack2((k10[r] + kbs[0]) * (k20[r] + kbs[0]),
                            (k11[r] + kbs[1]) * (k21[r] + kbs[1]));
        }
        // V global store (off the LDS-dependent path)
        char* bb = evbase + (size_t)(base + i) * 1536;
        float f00 = (v10[0] + vbs[0]) * (v20[0] + vbs[0]);
        float f01 = (v10[1] + vbs[0]) * (v20[1] + vbs[0]);
        float f02 = (v10[2] + vbs[0]) * (v20[2] + vbs[0]);
        float f03 = (v10[3] + vbs[0]) * (v20[3] + vbs[0]);
        float f10 = (v11[0] + vbs[1]) * (v21[0] + vbs[1]);
        float f11 = (v11[1] + vbs[1]) * (v21[1] + vbs[1]);
        float f12 = (v11[2] + vbs[1]) * (v21[2] + vbs[1]);
        float f13 = (v11[3] + vbs[1]) * (v21[3] + vbs[1]);
        uint2 st;
        st.x = pack2(f00, f01); st.y = pack2(f02, f03);
        *(uint2*)(bb + 512 + ((col) * 2 + (quad >> 1)) * 16 + (quad & 1) * 8) = st;
        st.x = pack2(f10, f11); st.y = pack2(f12, f13);
        *(uint2*)(bb + 512 + ((16 + col) * 2 + (quad >> 1)) * 16 + (quad & 1) * 8) = st;
    };

#pragma unroll
    for (int i = 0; i < 9; ++i) {
        s16x8 aq, bk;
        if (i >= 1) {   // issue frag reads for stage2(i-1), set (i-1)&1
            const int s = (i - 1) & 1;
            aq = *(const s16x8*)(qk[widx][s][0] + col * 40 + quad * 8);
            bk = *(const s16x8*)(qk[widx][s][1] + col * 40 + quad * 8);
        }
        if (i == 0) { issueL(0, 0); issueL(1, 1); }
        if (i < 8) stage1(i);
        if (i + 2 < 8) issueL(i & 1, i + 2);
        if (i >= 1) {
            // ---- stage2(i-1): norms, S, exp, E store ----
            float qv[8], ssq = 0.f, ssk = 0.f;
            for (int j = 0; j < 8; ++j) {
                qv[j] = bf2f((unsigned short)aq[j]); ssq += qv[j] * qv[j];
                float kf = bf2f((unsigned short)bk[j]); ssk += kf * kf;
            }
            ssq += __shfl_xor(ssq, 16); ssk += __shfl_xor(ssk, 16);
            ssq += __shfl_xor(ssq, 32); ssk += __shfl_xor(ssk, 32);
            float sq = 1.f / fmaxf(sqrtf(ssq), 1e-12f);
            float ik = 1.f / fmaxf(sqrtf(ssk), 1e-12f);
            uint4 uq;
            uq.x = pack2(qv[0] * sq, qv[1] * sq); uq.y = pack2(qv[2] * sq, qv[3] * sq);
            uq.z = pack2(qv[4] * sq, qv[5] * sq); uq.w = pack2(qv[6] * sq, qv[7] * sq);
            s16x8 aqs = __builtin_bit_cast(s16x8, uq);
            f32x4 S = MFMA(aqs, bk, z);   // S[c=quad*4+r][d=col] * ||K_d||
            float ex[4];
            for (int r = 0; r < 4; ++r) { ex[r] = __expf(S[r] * ik); dacc[r] += ex[r]; }
            uint2 st;
            st.x = pack2(ex[0], ex[1]); st.y = pack2(ex[2], ex[3]);
            *(uint2*)(evbase + (size_t)(base + i - 1) * 1536 + col * 32 + quad * 8) = st;
        }
    }

    // Hierarchical denominator reduce: regs -> block LDS -> 8 global partials
    for (int r = 0; r < 4; ++r)
        atomicAdd(&Dblk[col * 16 + quad * 4 + r], dacc[r]);
    __syncthreads();
    atomicAdd(((float*)ws) + ((blockIdx.x & 7) << 8) + tid, Dblk[tid]);
}

// ---------------------------------------------------------------------------
// k2: cooperative 4-wave block over ONE 16-batch group.  All global loads
// (D partials, 12 E/V frags, 12 p1wp frags) hoisted to the top so their
// latency overlaps the whole phase-1 compute.  Phase1 -> shared 16KB H;
// phase2 MFMA; partial reduce through LDS; wave0 tail.  Grid 4096.
// ---------------------------------------------------------------------------
__global__ __launch_bounds__(256, 3) void k2_apply(
    const char* __restrict__ ws, const float* __restrict__ p1b,
    const float* __restrict__ p2W, const float* __restrict__ p2b,
    float* __restrict__ out) {

    const int tid = threadIdx.x;
    const int lane = tid & 63;
    const int widx = tid >> 6;
    const int col = lane & 15;
    const int quad = lane >> 4;
    const int qm = quad & 1;        // mirrored address for upper quads

    __shared__ __align__(16) unsigned short Hs[16 * 512];   // 16 KiB
    float* P = (float*)Hs;          // aliased partial-sum buffer (12 KiB)

    const char* evbase = ws + WS_EV;
    const unsigned short* p1wp = (const unsigned short*)(ws + WS_P1W);
    const int g = blockIdx.x;
    const f32x4 z = {0.f, 0.f, 0.f, 0.f};
    const s16x8 zz = {0, 0, 0, 0, 0, 0, 0, 0};

    // ---- hoisted loads: D partials ----
    const float* Dws = (const float*)ws;
    float4 dpa[8], dpb[8];
    for (int p = 0; p < 8; ++p) {
        const float4* dp = (const float4*)(Dws + p * 256 + col * 16 + qm * 8);
        dpa[p] = dp[0]; dpb[p] = dp[1];
    }
    // ---- hoisted loads: E/V fragments for the 4 batches this wave handles ----
    s16x8 er[4], bv0[4], bv1[4];
    for (int ii = 0; ii < 4; ++ii) {
        const int b = g * 16 + widx * 4 + ii;
        const char* bbase = evbase + (size_t)b * 1536;
        er[ii]  = *(const s16x8*)(bbase + col * 32 + qm * 16);
        bv0[ii] = *(const s16x8*)(bbase + 512 + (col * 2 + qm) * 16);
        bv1[ii] = *(const s16x8*)(bbase + 512 + ((16 + col) * 2 + qm) * 16);
    }
    // ---- hoisted loads: p1wp B-frags for phase 2 (L2-hot) ----
    s16x8 bw[3][4];
    for (int nt = 0; nt < 3; ++nt)
        for (int t = 0; t < 4; ++t)
            bw[nt][t] = *(const s16x8*)(p1wp + ((nt * 16 + widx * 4 + t) * 64 + lane) * 8);

    // dinv from partial sums
    float dinv[8];
    {
        float ds0[8] = {0, 0, 0, 0, 0, 0, 0, 0};
        for (int p = 0; p < 8; ++p) {
            ds0[0] += dpa[p].x; ds0[1] += dpa[p].y; ds0[2] += dpa[p].z; ds0[3] += dpa[p].w;
            ds0[4] += dpb[p].x; ds0[5] += dpb[p].y; ds0[6] += dpb[p].z; ds0[7] += dpb[p].w;
        }
        for (int j = 0; j < 8; ++j) dinv[j] = 1.f / ds0[j];
    }

    // Phase 1: out[d][e] for batches i = widx*4 .. +3 -> H rows (bf16, swizzled)
    for (int ii = 0; ii < 4; ++ii) {
        const int i = widx * 4 + ii;
        float ef[8];
        for (int j = 0; j < 8; ++j)
            ef[j] = bf2f((unsigned short)er[ii][j]) * dinv[j];
        uint4 ua;
        ua.x = pack2(ef[0], ef[1]); ua.y = pack2(ef[2], ef[3]);
        ua.z = pack2(ef[4], ef[5]); ua.w = pack2(ef[6], ef[7]);
        s16x8 afrag = __builtin_bit_cast(s16x8, ua);
        s16x8 b0 = bv0[ii], b1 = bv1[ii];
        if (quad >= 2) { afrag = zz; b0 = zz; b1 = zz; }  // K-padding (c>=16 -> 0)
        f32x4 o0 = MFMA(afrag, b0, z);   // out[d=quad*4+r][e=col]
        f32x4 o1 = MFMA(afrag, b1, z);   // out[d=quad*4+r][e=col+16]
        uint4 uh;
        uh.x = pack2(o0[0], o0[1]); uh.y = pack2(o0[2], o0[3]);
        uh.z = pack2(o1[0], o1[1]); uh.w = pack2(o1[2], o1[3]);
        int chunk = (col * 4 + quad) ^ (i & 7);   // 16B-chunk XOR swizzle
        *(uint4*)(Hs + i * 512 + chunk * 8) = uh;
    }
    __syncthreads();

    // Phase 2: MLP1 — H[16 x 512] @ p1Wp^T, wave widx handles kt = widx*4..+3
    f32x4 acc[3] = {z, z, z};
    for (int t = 0; t < 4; ++t) {
        int kt = widx * 4 + t;
        int chunk = (kt * 4 + quad) ^ (col & 7);
        s16x8 a = *(const s16x8*)(Hs + col * 512 + chunk * 8);
        for (int nt = 0; nt < 3; ++nt)
            acc[nt] = MFMA(a, bw[nt][t], acc[nt]);
    }
    __syncthreads();   // H reads done before P overwrites it

    // partials -> LDS: P[widx][lane][nt*4+r], lane stride 12 floats (48B)
    for (int nt = 0; nt < 3; ++nt)
        *(f32x4*)(P + (widx * 64 + lane) * 12 + nt * 4) = acc[nt];
    __syncthreads();

    if (widx == 0) {
        // Phase 3: sum partials, bias+relu, MLP2, 16-lane butterfly, normalize
        f32x4 s[3] = {z, z, z};
        for (int w = 0; w < 4; ++w)
            for (int nt = 0; nt < 3; ++nt) {
                f32x4 pv = *(const f32x4*)(P + (w * 64 + lane) * 12 + nt * 4);
                s[nt] += pv;
            }
        float p2w[3][3], p1bias[3];
        for (int nt = 0; nt < 3; ++nt) {
            p1bias[nt] = p1b[col + 16 * nt];
            for (int t = 0; t < 3; ++t) p2w[nt][t] = p2W[t * 48 + col + 16 * nt];
        }
        const float pb0 = p2b[0], pb1 = p2b[1], pb2 = p2b[2];
        float pp[4][3] = {};
        for (int nt = 0; nt < 3; ++nt)
            for (int r = 0; r < 4; ++r) {
                float hv = fmaxf(s[nt][r] + p1bias[nt], 0.f);
                pp[r][0] += hv * p2w[nt][0];
                pp[r][1] += hv * p2w[nt][1];
                pp[r][2] += hv * p2w[nt][2];
            }
        for (int m = 1; m <= 8; m <<= 1)
            for (int r = 0; r < 4; ++r)
                for (int t = 0; t < 3; ++t)
                    pp[r][t] += __shfl_xor(pp[r][t], m);
        for (int r = 0; r < 4; ++r) {
            float h0 = pp[r][0] + pb0, h1 = pp[r][1] + pb1, h2 = pp[r][2] + pb2;
            float inv = 1.f / fmaxf(sqrtf(h0 * h0 + h1 * h1 + h2 * h2), 1e-12f);
            if (col < 3) {
                float v = (col == 0) ? h0 : ((col == 1) ? h1 : h2);
                out[(size_t)(g * 16 + quad * 4 + r) * 3 + col] = v * inv;
            }
        }
    }
}

// ---------------------------------------------------------------------------
extern "C" void kernel_launch(void* const* d_in, const int* in_sizes, int n_in,
                              void* d_out, int out_size, void* d_ws, size_t ws_size,
                              hipStream_t stream) {
    const float* e1  = (const float*)d_in[0];
    const float* e2  = (const float*)d_in[1];
    const float* qW  = (const float*)d_in[2];
    const float* qb  = (const float*)d_in[3];
    const float* kW  = (const float*)d_in[4];
    const float* kb  = (const float*)d_in[5];
    const float* vW  = (const float*)d_in[6];
    const float* vb  = (const float*)d_in[7];
    const float* p1W = (const float*)d_in[8];
    const float* p1b = (const float*)d_in[9];
    const float* p2W = (const float*)d_in[10];
    const float* p2b = (const float*)d_in[11];
    float* out = (float*)d_out;
    char* ws = (char*)d_ws;

    k0_prep<<<96, 256, 0, stream>>>(p1W, ws);
    k1_stats<<<2048, 256, 0, stream>>>(e1, e2, qW, qb, kW, kb, vW, vb, ws);
    k2_apply<<<4096, 256, 0, stream>>>(ws, p1b, p2W, p2b, out);
}